// Round 8
// baseline (750.057 us; speedup 1.0000x reference)
//
#include <hip/hip_runtime.h>
#include <hip/hip_bf16.h>
#include <math.h>

typedef __attribute__((ext_vector_type(8))) short bf16x8;
typedef __attribute__((ext_vector_type(4))) float f32x4;

__device__ __forceinline__ unsigned short f2b(float f) {
  unsigned u = __float_as_uint(f);
  unsigned r = (u + 0x7FFF + ((u >> 16) & 1)) >> 16;
  return (unsigned short)r;
}

__device__ __forceinline__ void async16(const void* g, void* l) {
  __builtin_amdgcn_global_load_lds(
      (const __attribute__((address_space(1))) unsigned int*)(g),
      (__attribute__((address_space(3))) unsigned int*)(l), 16, 0, 0);
}

// Sum across the 16 lanes of a DPP row (lanes 16k..16k+15) via row_ror.
__device__ __forceinline__ float rowsum16(float x) {
  x += __int_as_float(__builtin_amdgcn_update_dpp(0, __float_as_int(x), 0x121, 0xF, 0xF, false));
  x += __int_as_float(__builtin_amdgcn_update_dpp(0, __float_as_int(x), 0x122, 0xF, 0xF, false));
  x += __int_as_float(__builtin_amdgcn_update_dpp(0, __float_as_int(x), 0x124, 0xF, 0xF, false));
  x += __int_as_float(__builtin_amdgcn_update_dpp(0, __float_as_int(x), 0x128, 0xF, 0xF, false));
  return x;
}

// v_fma_mix_f32: d = a(f32) * f16half(pk) + c(f32). No unpack instructions.
__device__ __forceinline__ float mixhi(float a, unsigned pk, float c) {
  float d;
  asm("v_fma_mix_f32 %0, %1, %2, %3 op_sel:[0,1,0] op_sel_hi:[0,1,0]"
      : "=v"(d) : "v"(a), "v"(pk), "v"(c));
  return d;
}
__device__ __forceinline__ float mixlo(float a, unsigned pk, float c) {
  float d;
  asm("v_fma_mix_f32 %0, %1, %2, %3 op_sel:[0,0,0] op_sel_hi:[0,1,0]"
      : "=v"(d) : "v"(a), "v"(pk), "v"(c));
  return d;
}
__device__ __forceinline__ float h2f(unsigned h) {
  float f; asm("v_cvt_f32_f16 %0, %1" : "=v"(f) : "v"(h)); return f;
}

// ---------------------------------------------------------------------------
// fp32 -> bf16 converts: x, R|K|V (concatenated 3072x2048) AND Ow, one launch.
// ---------------------------------------------------------------------------
__global__ __launch_bounds__(256) void cvt4_kernel(
    const float* __restrict__ x, const float* __restrict__ R,
    const float* __restrict__ K, const float* __restrict__ V,
    const float* __restrict__ Ow,
    unsigned short* __restrict__ xb, unsigned short* __restrict__ RKVb,
    unsigned short* __restrict__ Ob)
{
  const int bid = blockIdx.x;
  const float* s; unsigned short* d; int i;
  if (bid < 8192)       { s = x; d = xb; i = bid * 256 + threadIdx.x; }
  else if (bid < 12288) { s = R; d = RKVb; i = (bid - 8192) * 256 + threadIdx.x; }
  else if (bid < 13312) { s = K; d = RKVb + 2048 * 2048; i = (bid - 12288) * 256 + threadIdx.x; }
  else if (bid < 14336) { s = V; d = RKVb + 2560 * 2048; i = (bid - 13312) * 256 + threadIdx.x; }
  else                  { s = Ow; d = Ob; i = (bid - 14336) * 256 + threadIdx.x; }
  float4 v = ((const float4*)s)[i];
  ushort4 o;
  o.x = f2b(v.x); o.y = f2b(v.y); o.z = f2b(v.z); o.w = f2b(v.w);
  ((ushort4*)d)[i] = o;
}

// ---------------------------------------------------------------------------
// Transposed converts, all 6 small matrices in ONE launch (192 blocks):
// out[n*ors + k] = bf16(in[k*Nd + n]).
// ---------------------------------------------------------------------------
__global__ __launch_bounds__(256) void tcvt_all(
    const float* __restrict__ w1, const float* __restrict__ a1,
    const float* __restrict__ v1, const float* __restrict__ w2,
    const float* __restrict__ a2, const float* __restrict__ v2,
    unsigned short* __restrict__ Bcat, unsigned short* __restrict__ w2t,
    unsigned short* __restrict__ a2t, unsigned short* __restrict__ v2t)
{
  const int r = blockIdx.x >> 5, i = blockIdx.x & 31;
  const float* in; unsigned short* out; int Kd, Nd, ors, bx, by;
  switch (r) {
    case 0:  in = w1; out = Bcat;             Kd = 2048; Nd = 64;   ors = 2048; bx = 0; by = i; break;
    case 1:  in = a1; out = Bcat + 64 * 2048; Kd = 2048; Nd = 64;   ors = 2048; bx = 0; by = i; break;
    case 2:  in = v1; out = Bcat + 128 * 2048; Kd = 2048; Nd = 32;  ors = 2048; bx = 0; by = i; break;
    case 3:  in = w2; out = w2t;              Kd = 64;   Nd = 2048; ors = 64;   bx = i; by = 0; break;
    case 4:  in = a2; out = a2t;              Kd = 64;   Nd = 2048; ors = 64;   bx = i; by = 0; break;
    default: in = v2; out = v2t;              Kd = 32;   Nd = 2048; ors = 32;   bx = i; by = 0; break;
  }
  __shared__ unsigned short tile[64][65];
  const int tx = threadIdx.x & 63, ty = threadIdx.x >> 6;
  const int n0 = bx * 64, k0 = by * 64;
  #pragma unroll
  for (int j = 0; j < 16; ++j) {
    const int k = k0 + j * 4 + ty;
    const int n = n0 + tx;
    unsigned short v = 0;
    if (k < Kd && n < Nd) v = f2b(in[(size_t)k * Nd + n]);
    tile[j * 4 + ty][tx] = v;
  }
  __syncthreads();
  #pragma unroll
  for (int j = 0; j < 16; ++j) {
    const int n = n0 + j * 4 + ty;
    const int k = k0 + tx;
    if (n < Nd && k < Kd) out[(size_t)n * ors + k] = tile[tx][j * 4 + ty];
  }
}

// ---------------------------------------------------------------------------
// bf16 MFMA GEMM body: C[M,N] = A[M,K] @ B[N,K]^T (+bias). 128x128 tile, BK=32.
// ---------------------------------------------------------------------------
template<int OUTBF16, int ACT>
__device__ __forceinline__ void gemm_body(
    const unsigned short* __restrict__ A, int lda,
    const unsigned short* __restrict__ B, int ldb,
    const float* __restrict__ bias, void* __restrict__ Cv, int ldc,
    int M, int N, int K, int row0, int col0)
{
  __shared__ __align__(16) unsigned short As[128 * 32];
  __shared__ __align__(16) unsigned short Bs[128 * 32];
  const int tid = threadIdx.x;
  const int w = tid >> 6, lane = tid & 63;
  const int wr = (w >> 1) * 64, wc = (w & 1) * 64;

  f32x4 acc[4][4];
  #pragma unroll
  for (int i = 0; i < 4; ++i)
    #pragma unroll
    for (int j = 0; j < 4; ++j)
      acc[i][j] = (f32x4){0.f, 0.f, 0.f, 0.f};

  const int srow = w * 32 + (lane >> 2);
  const int scol = (lane & 3) * 8;
  const int brow0 = (col0 + srow < N) ? (col0 + srow) : 0;
  const int brow1 = (col0 + srow + 16 < N) ? (col0 + srow + 16) : 0;
  const unsigned short* gA0 = A + (size_t)(row0 + srow) * lda + scol;
  const unsigned short* gA1 = gA0 + (size_t)16 * lda;
  const unsigned short* gB0 = B + (size_t)brow0 * ldb + scol;
  const unsigned short* gB1 = B + (size_t)brow1 * ldb + scol;
  unsigned short* lA0 = As + w * 1024;
  unsigned short* lA1 = As + w * 1024 + 512;
  unsigned short* lB0 = Bs + w * 1024;
  unsigned short* lB1 = Bs + w * 1024 + 512;

  const int m16 = lane & 15;
  const int q8  = (lane >> 4) * 8;

  for (int k0 = 0; k0 < K; k0 += 32) {
    async16(gA0, lA0);
    async16(gA1, lA1);
    async16(gB0, lB0);
    async16(gB1, lB1);
    gA0 += 32; gA1 += 32; gB0 += 32; gB1 += 32;
    __syncthreads();
    bf16x8 af[4], bfr[4];
    #pragma unroll
    for (int i = 0; i < 4; ++i) {
      af[i]  = *(const bf16x8*)(As + (wr + i * 16 + m16) * 32 + q8);
      bfr[i] = *(const bf16x8*)(Bs + (wc + i * 16 + m16) * 32 + q8);
    }
    #pragma unroll
    for (int i = 0; i < 4; ++i)
      #pragma unroll
      for (int j = 0; j < 4; ++j)
        acc[i][j] = __builtin_amdgcn_mfma_f32_16x16x32_bf16(af[i], bfr[j], acc[i][j], 0, 0, 0);
    __syncthreads();
  }

  #pragma unroll
  for (int j = 0; j < 4; ++j) {
    const int c_ = col0 + wc + j * 16 + (lane & 15);
    if (c_ < N) {
      const float bv = bias ? bias[c_] : 0.f;
      #pragma unroll
      for (int i = 0; i < 4; ++i) {
        const int r_ = row0 + wr + i * 16 + (lane >> 4) * 4;
        #pragma unroll
        for (int t4 = 0; t4 < 4; ++t4) {
          float v = acc[i][j][t4] + bv;
          if (ACT == 2 && c_ < 64) v = tanhf(v);
          if (OUTBF16)
            ((unsigned short*)Cv)[(size_t)(r_ + t4) * ldc + c_] = f2b(v);
          else
            ((float*)Cv)[(size_t)(r_ + t4) * ldc + c_] = v;
        }
      }
    }
  }
}

// Output projection, 1-D grid 512 with XCD-chunked swizzle (512 = 8*64):
// blocks on one XCD cover contiguous lb -> 4 full row-panels share A in L2.
__global__ __launch_bounds__(256) void gemm_out(
    const unsigned short* __restrict__ A,
    const unsigned short* __restrict__ B,
    const float* __restrict__ bias, float* __restrict__ C)
{
  const int lb = (blockIdx.x & 7) * 64 + (blockIdx.x >> 3);
  const int bx = lb & 15, by = lb >> 4;
  gemm_body<0, 0>(A, 2048, B, 2048, bias, C, 2048, 4096, 2048, 2048,
                  by * 128, bx * 128);
}

// Merged low-rank stage-2: blockIdx.z selects (w | a | v) region.
__global__ __launch_bounds__(256) void gemm_lr2(
    const unsigned short* __restrict__ hcat,
    const unsigned short* __restrict__ w2t,
    const unsigned short* __restrict__ a2t,
    const unsigned short* __restrict__ v2t,
    float* __restrict__ wt, float* __restrict__ at, float* __restrict__ vt)
{
  const int z = blockIdx.z;
  const unsigned short* A; const unsigned short* Bm; float* C; int K;
  if (z == 0)      { A = hcat;       Bm = w2t; C = wt; K = 64; }
  else if (z == 1) { A = hcat + 64;  Bm = a2t; C = at; K = 64; }
  else             { A = hcat + 128; Bm = v2t; C = vt; K = 32; }
  gemm_body<0, 0>(A, 160, Bm, K, nullptr, C, 2048, 4096, 2048, K,
                  blockIdx.y * 128, blockIdx.x * 128);
}

// ---------------------------------------------------------------------------
// Merged R|K|V|H projection GEMM: B is RKVb||Bcat = (3232 x 2048) bf16.
// 1-D grid 832 with XCD-chunked swizzle (832 = 8*104): contiguous lb per
// XCD -> 4 row-panels of A reused from that XCD's L2.
// ---------------------------------------------------------------------------
__global__ __launch_bounds__(256) void gemm_rkvh(
    const unsigned short* __restrict__ A, const unsigned short* __restrict__ B,
    const float* __restrict__ Rb_, const float* __restrict__ Kb_,
    const float* __restrict__ Vb_,
    float* __restrict__ Cr, float* __restrict__ Ck, float* __restrict__ Cvv,
    unsigned short* __restrict__ hcat)
{
  const int lb = (blockIdx.x & 7) * 104 + (blockIdx.x >> 3);
  const int col0 = (lb % 26) * 128;
  const int row0 = (lb / 26) * 128;
  float* Cf = nullptr; unsigned short* Ch = nullptr;
  int ldc, cbase; const float* bias = nullptr;
  if (col0 < 2048)      { Cf = Cr;  ldc = 2048; cbase = col0;        bias = Rb_; }
  else if (col0 < 2560) { Cf = Ck;  ldc = 512;  cbase = col0 - 2048; bias = Kb_; }
  else if (col0 < 3072) { Cf = Cvv; ldc = 512;  cbase = col0 - 2560; bias = Vb_; }
  else                  { Ch = hcat; ldc = 160; cbase = col0 - 3072; }

  __shared__ __align__(16) unsigned short As[128 * 32];
  __shared__ __align__(16) unsigned short Bs[128 * 32];
  const int tid = threadIdx.x;
  const int w = tid >> 6, lane = tid & 63;
  const int wr = (w >> 1) * 64, wc = (w & 1) * 64;

  f32x4 acc[4][4];
  #pragma unroll
  for (int i = 0; i < 4; ++i)
    #pragma unroll
    for (int j = 0; j < 4; ++j)
      acc[i][j] = (f32x4){0.f, 0.f, 0.f, 0.f};

  const int srow = w * 32 + (lane >> 2);
  const int scol = (lane & 3) * 8;
  const int brow0 = (col0 + srow < 3232) ? (col0 + srow) : 0;
  const int brow1 = (col0 + srow + 16 < 3232) ? (col0 + srow + 16) : 0;
  const unsigned short* gA0 = A + (size_t)(row0 + srow) * 2048 + scol;
  const unsigned short* gA1 = gA0 + (size_t)16 * 2048;
  const unsigned short* gB0 = B + (size_t)brow0 * 2048 + scol;
  const unsigned short* gB1 = B + (size_t)brow1 * 2048 + scol;
  unsigned short* lA0 = As + w * 1024;
  unsigned short* lA1 = As + w * 1024 + 512;
  unsigned short* lB0 = Bs + w * 1024;
  unsigned short* lB1 = Bs + w * 1024 + 512;

  const int m16 = lane & 15;
  const int q8  = (lane >> 4) * 8;

  for (int k0 = 0; k0 < 2048; k0 += 32) {
    async16(gA0, lA0);
    async16(gA1, lA1);
    async16(gB0, lB0);
    async16(gB1, lB1);
    gA0 += 32; gA1 += 32; gB0 += 32; gB1 += 32;
    __syncthreads();
    bf16x8 af[4], bfr[4];
    #pragma unroll
    for (int i = 0; i < 4; ++i) {
      af[i]  = *(const bf16x8*)(As + (wr + i * 16 + m16) * 32 + q8);
      bfr[i] = *(const bf16x8*)(Bs + (wc + i * 16 + m16) * 32 + q8);
    }
    #pragma unroll
    for (int i = 0; i < 4; ++i)
      #pragma unroll
      for (int j = 0; j < 4; ++j)
        acc[i][j] = __builtin_amdgcn_mfma_f32_16x16x32_bf16(af[i], bfr[j], acc[i][j], 0, 0, 0);
    __syncthreads();
  }

  #pragma unroll
  for (int j = 0; j < 4; ++j) {
    const int c_ = cbase + wc + j * 16 + (lane & 15);
    if (Ch) {
      if (c_ < 160) {
        #pragma unroll
        for (int i = 0; i < 4; ++i) {
          const int r_ = row0 + wr + i * 16 + (lane >> 4) * 4;
          #pragma unroll
          for (int t4 = 0; t4 < 4; ++t4) {
            float v = acc[i][j][t4];
            if (c_ < 64) v = tanhf(v);
            Ch[(size_t)(r_ + t4) * 160 + c_] = f2b(v);
          }
        }
      }
    } else {
      const float bv = bias[c_];
      #pragma unroll
      for (int i = 0; i < 4; ++i) {
        const int r_ = row0 + wr + i * 16 + (lane >> 4) * 4;
        #pragma unroll
        for (int t4 = 0; t4 < 4; ++t4)
          Cf[(size_t)(r_ + t4) * ldc + c_] = acc[i][j][t4] + bv;
      }
    }
  }
}

// ---------------------------------------------------------------------------
// Elementwise prep. Packs scan streams as f16 pairs (v_cvt_pkrtz):
//   rk_pk[idx] = [hi=f16(k_final) | lo=f16(r)]
//   ab_pk[idx] = [hi=f16(aa)      | lo=f16(bb)]
// decay (wt) and v_final (vt) stay f32 (decay compounds over 1024 steps).
// ---------------------------------------------------------------------------
__global__ __launch_bounds__(256) void prep_kernel(
    const float* __restrict__ k_buf, const float* __restrict__ v_buf,
    const float* __restrict__ r_buf,
    float* wt_decay, const float* __restrict__ at, float* vt_vf,
    const float* __restrict__ v_first,
    const float* __restrict__ w0, const float* __restrict__ a0,
    const float* __restrict__ v0, const float* __restrict__ k_k,
    const float* __restrict__ k_a,
    unsigned* __restrict__ rk_pk, unsigned* __restrict__ ab_pk)
{
  const int row = blockIdx.x;
  const int tid = threadIdx.x;
  const int c0 = tid << 3;
  const int h = tid >> 3;
  const int kvoff = (h >> 2) << 6;
  const size_t base = (size_t)row * 2048;
  const size_t kvrow = (size_t)row * 512;
  float kr[8], kkr[8];
  float ss = 0.f;
  #pragma unroll
  for (int e = 0; e < 8; ++e) {
    const int c = c0 + e;
    const float kv = k_buf[kvrow + kvoff + (c & 63)];
    kr[e] = kv;
    const float t = kv * k_k[c];
    kkr[e] = t;
    ss = fmaf(t, t, ss);
  }
  ss += __shfl_xor(ss, 1);
  ss += __shfl_xor(ss, 2);
  ss += __shfl_xor(ss, 4);
  const float inv = 1.f / fmaxf(sqrtf(ss), 1e-12f);
  #pragma unroll
  for (int e = 0; e < 8; ++e) {
    const int c = c0 + e;
    const size_t idx = base + c;
    const float kk = kkr[e] * inv;
    const float a = 1.f / (1.f + expf(-(a0[c] + at[idx])));
    const float u = w0[c] + wt_decay[idx];
    const float sig_u = 1.f / (1.f + expf(-u));
    wt_decay[idx] = expf(-0.5488116360940264f * sig_u);
    const float kfin = kr[e] * fmaf(a - 1.f, k_a[c], 1.f);
    const float vr = v_buf[kvrow + kvoff + (c & 63)];
    const float sv = 1.f / (1.f + expf(-(v0[c] + vt_vf[idx])));
    vt_vf[idx] = vr + (v_first[idx] - vr) * sv;
    const float bbv = kk * a;
    const float aav = -kk;
    unsigned rk_u, ab_u;
    asm("v_cvt_pkrtz_f16_f32 %0, %1, %2" : "=v"(rk_u) : "v"(r_buf[idx]), "v"(kfin));
    asm("v_cvt_pkrtz_f16_f32 %0, %1, %2" : "=v"(ab_u) : "v"(bbv), "v"(aav));
    rk_pk[idx] = rk_u;
    ab_pk[idx] = ab_u;
  }
}

// ---------------------------------------------------------------------------
// RWKV-7 scan — 2 ROWS PER LANE. 256 blocks (1/CU), 4 waves x 8 rows: lane
// (rg,colg) holds S0=S[r][4colg..+3], S1=S[r+1][...] (r = half*32+widx*8+rg*2).
// Each stream b128 read now serves TWO rows: per-CU LDS work halves to
// 4 waves x (3xb128 + 1xb64) ~= 172 cyc/step (was 334 at 8 waves).
// 1 wave/SIMD latency is covered by the depth-2 register pipeline (absent in
// round 3's failed attempt) + chunk-ahead staging with counted vmcnt.
// Ladder (STAGE=7 ops, YSTORE=1): WB(7) chunk0, WB(8) steady, WB(1) last.
// GroupNorm partials fused (2 per bh).
// ---------------------------------------------------------------------------
#define WB(n) asm volatile("s_waitcnt vmcnt(" #n ") lgkmcnt(0)\n\ts_barrier" ::: "memory")
#define BAR2() asm volatile("s_waitcnt lgkmcnt(0)\n\ts_barrier" ::: "memory")

__global__ __launch_bounds__(256) void scan_kernel(
    const unsigned* __restrict__ rkB, const unsigned* __restrict__ abB,
    const float* __restrict__ dB, const float* __restrict__ vB,
    const float* __restrict__ state, float* __restrict__ y,
    float* __restrict__ part)
{
  // LDS words: buf[p] at p*7168: rk[32][64] u32 @0, ab @2048, d[32][64] f32
  // @4096, v[32][32] f32 @6144. y @14336 ([32][32]). Total 15360 w = 61440 B.
  __shared__ float lds[15360];
  unsigned* ldsU = (unsigned*)lds;
  const int tid = threadIdx.x;
  const int bid = blockIdx.x;
  const int xcd = bid & 7, bj = bid >> 3;      // bj in [0,32)
  const int half = bj & 1, bhq = bj >> 1;      // bhq in [0,16)
  const int bh = (bhq << 3) | xcd;             // [0,128); both halves on one XCD
  const int widx = tid >> 6;
  const int lane = tid & 63;
  const int rg = lane >> 4;
  const int colg = lane & 15;
  const int r0b = (widx << 3) + (rg << 1);     // [0,32), even
  const int row = (half << 5) + r0b;           // [0,64)
  const int b = bh >> 5, h = bh & 31;

  float4 S0 = *(const float4*)(state + (size_t)bh * 4096 + row * 64 + (colg << 2));
  float4 S1 = *(const float4*)(state + (size_t)bh * 4096 + (row + 1) * 64 + (colg << 2));

  const unsigned cb = (unsigned)((b * 1024) * 2048 + h * 64);
  const unsigned sstep = (unsigned)(tid >> 4);        // staging step 0..15
  const unsigned scol  = (unsigned)((tid & 15) << 2); // staging col word
  const unsigned vstep = (unsigned)(tid >> 3);        // v/y step 0..31
  const unsigned vcol  = (unsigned)((tid & 7) << 2);  // v/y 4-float col

  float sacc = 0.f, ssacc = 0.f;
  const float fzero = 0.0f;

  #define STAGE(step0, bofs) do {                                            \
    const unsigned g0_ = cb + ((step0) + sstep) * 2048u + scol;              \
    const unsigned g1_ = g0_ + 16u * 2048u;                                  \
    async16(rkB + g0_, ldsU + (bofs) + tid * 4);                             \
    async16(rkB + g1_, ldsU + (bofs) + 1024 + tid * 4);                      \
    async16(abB + g0_, ldsU + (bofs) + 2048 + tid * 4);                      \
    async16(abB + g1_, ldsU + (bofs) + 3072 + tid * 4);                      \
    async16(dB + g0_,  lds + (bofs) + 4096 + tid * 4);                       \
    async16(dB + g1_,  lds + (bofs) + 5120 + tid * 4);                       \
    const unsigned gv_ = cb + ((step0) + vstep) * 2048u                      \
                         + (unsigned)(half << 5) + vcol;                     \
    async16(vB + gv_, lds + (bofs) + 6144 + tid * 4);                        \
  } while (0)

  #define LDRK(bofs, s) (*(const uint4*)(ldsU + (bofs) + (s) * 64 + (colg << 2)))
  #define LDAB(bofs, s) (*(const uint4*)(ldsU + (bofs) + 2048 + (s) * 64 + (colg << 2)))
  #define LDD(bofs, s)  (*(const float4*)(lds + (bofs) + 4096 + (s) * 64 + (colg << 2)))
  #define LDV(bofs, s)  (*(const float2*)(lds + (bofs) + 6144 + (s) * 32 + r0b))

  #define STEPBODY(rkc, abc, dvc, vvc, s) do {                               \
    float t0a = mixhi(S0.x, abc.x, fzero);                                   \
    t0a = mixhi(S0.y, abc.y, t0a);                                           \
    t0a = mixhi(S0.z, abc.z, t0a);                                           \
    t0a = mixhi(S0.w, abc.w, t0a);                                           \
    float t0b = mixhi(S1.x, abc.x, fzero);                                   \
    t0b = mixhi(S1.y, abc.y, t0b);                                           \
    t0b = mixhi(S1.z, abc.z, t0b);                                           \
    t0b = mixhi(S1.w, abc.w, t0b);                                           \
    const float sa0 = rowsum16(t0a);                                         \
    const float sa1 = rowsum16(t0b);                                         \
    float p00 = mixhi(vvc.x, rkc.x, fzero);                                  \
    float p01 = mixhi(vvc.x, rkc.y, fzero);                                  \
    float p02 = mixhi(vvc.x, rkc.z, fzero);                                  \
    float p03 = mixhi(vvc.x, rkc.w, fzero);                                  \
    float p10 = mixhi(vvc.y, rkc.x, fzero);                                  \
    float p11 = mixhi(vvc.y, rkc.y, fzero);                                  \
    float p12 = mixhi(vvc.y, rkc.z, fzero);                                  \
    float p13 = mixhi(vvc.y, rkc.w, fzero);                                  \
    p00 = mixlo(sa0, abc.x, p00);                                            \
    p01 = mixlo(sa0, abc.y, p01);                                            \
    p02 = mixlo(sa0, abc.z, p02);                                            \
    p03 = mixlo(sa0, abc.w, p03);                                            \
    p10 = mixlo(sa1, abc.x, p10);                                            \
    p11 = mixlo(sa1, abc.y, p11);                                            \
    p12 = mixlo(sa1, abc.z, p12);                                            \
    p13 = mixlo(sa1, abc.w, p13);                                            \
    S0.x = fmaf(S0.x, dvc.x, p00);                                           \
    S0.y = fmaf(S0.y, dvc.y, p01);                                           \
    S0.z = fmaf(S0.z, dvc.z, p02);                                           \
    S0.w = fmaf(S0.w, dvc.w, p03);                                           \
    S1.x = fmaf(S1.x, dvc.x, p10);                                           \
    S1.y = fmaf(S1.y, dvc.y, p11);                                           \
    S1.z = fmaf(S1.z, dvc.z, p12);                                           \
    S1.w = fmaf(S1.w, dvc.w, p13);                                           \
    float t1a = mixlo(S0.x, rkc.x, fzero);                                   \
    t1a = mixlo(S0.y, rkc.y, t1a);                                           \
    t1a = mixlo(S0.z, rkc.z, t1a);                                           \
    t1a = mixlo(S0.w, rkc.w, t1a);                                           \
    float t1b = mixlo(S1.x, rkc.x, fzero);                                   \
    t1b = mixlo(S1.y, rkc.y, t1b);                                           \
    t1b = mixlo(S1.z, rkc.z, t1b);                                           \
    t1b = mixlo(S1.w, rkc.w, t1b);                                           \
    const float y0 = rowsum16(t1a);                                          \
    const float y1 = rowsum16(t1b);                                          \
    if (colg == 0) {                                                         \
      *(float2*)(lds + 14336 + ((s) << 5) + r0b) = make_float2(y0, y1);      \
      sacc += y0 + y1;                                                       \
      ssacc = fmaf(y0, y0, fmaf(y1, y1, ssacc));                             \
    }                                                                        \
  } while (0)

  #define PROCESS(bofs) do {                                                 \
    uint4 rk0 = LDRK(bofs, 0), ab0 = LDAB(bofs, 0);                          \
    float4 dv0 = LDD(bofs, 0); float2 vv0 = LDV(bofs, 0);                    \
    uint4 rk1 = LDRK(bofs, 1), ab1 = LDAB(bofs, 1);                          \
    float4 dv1 = LDD(bofs, 1); float2 vv1 = LDV(bofs, 1);                    \
    _Pragma("unroll")                                                        \
    for (int s = 0; s < 32; ++s) {                                           \
      const bool ev = ((s & 1) == 0);                                        \
      const uint4 rkc = ev ? rk0 : rk1;                                      \
      const uint4 abc = ev ? ab0 : ab1;                                      \
      const float4 dvc = ev ? dv0 : dv1;                                     \
      const float2 vvc = ev ? vv0 : vv1;                                     \
      if (s < 30) {                                                          \
        if (ev) {                                                            \
          rk0 = LDRK(bofs, s + 2); ab0 = LDAB(bofs, s + 2);                  \
          dv0 = LDD(bofs, s + 2);  vv0 = LDV(bofs, s + 2);                   \
        } else {                                                             \
          rk1 = LDRK(bofs, s + 2); ab1 = LDAB(bofs, s + 2);                  \
          dv1 = LDD(bofs, s + 2);  vv1 = LDV(bofs, s + 2);                   \
        }                                                                    \
      }                                                                      \
      STEPBODY(rkc, abc, dvc, vvc, s);                                       \
    }                                                                        \
  } while (0)

  #define YSTORE(step0) do {                                                 \
    const float4 yv_ = *(const float4*)(lds + 14336 + tid * 4);              \
    *(float4*)(y + cb + ((step0) + vstep) * 2048u                            \
               + (unsigned)(half << 5) + vcol) = yv_;                        \
  } while (0)

  STAGE(0u, 0);
  STAGE(32u, 7168);

  // chunk 0
  WB(7);
  PROCESS(0);
  BAR2();
  YSTORE(0u);
  STAGE(64u, 0);

  // chunks 1..30
  for (int c = 1; c <= 30; ++c) {
    const int bofs = (c & 1) ? 7168 : 0;
    WB(8);
    PROCESS(bofs);
    BAR2();
    YSTORE((unsigned)(c << 5));
    if (c < 30) STAGE((unsigned)((c + 2) << 5), bofs);
  }

  // chunk 31
  WB(1);
  PROCESS(7168);
  BAR2();
  YSTORE(992u);

  // groupnorm partial for this (bh, half): valid in colg==0 lanes.
  sacc  += __shfl_xor(sacc, 16);
  sacc  += __shfl_xor(sacc, 32);
  ssacc += __shfl_xor(ssacc, 16);
  ssacc += __shfl_xor(ssacc, 32);
  __syncthreads();
  if (lane == 0) { lds[widx] = sacc; lds[4 + widx] = ssacc; }
  __syncthreads();
  if (tid == 0) {
    const float s_  = lds[0] + lds[1] + lds[2] + lds[3];
    const float ss_ = lds[4] + lds[5] + lds[6] + lds[7];
    ((float2*)part)[(bh << 1) + half] = make_float2(s_, ss_);
  }

  #undef STAGE
  #undef PROCESS
  #undef STEPBODY
  #undef YSTORE
  #undef LDRK
  #undef LDAB
  #undef LDD
  #undef LDV
}

// ---------------------------------------------------------------------------
// GroupNorm pass B + bonus: per-(b,t) row, writes xx in bf16.
// r,k for the bonus come from the packed f16 rk stream. 2 partials per bh.
// ---------------------------------------------------------------------------
__global__ __launch_bounds__(256) void gapply_kernel(
    const float* __restrict__ y, const unsigned* __restrict__ rkB,
    const float* __restrict__ vf,
    const float* __restrict__ part, const float* __restrict__ r_k,
    const float* __restrict__ ln_w, const float* __restrict__ ln_b,
    unsigned short* __restrict__ xxb)
{
  const int row = blockIdx.x;        // b*1024 + t
  const int b = row >> 10;
  const int tid = threadIdx.x;
  const int h = tid >> 3;
  const int bh = b * 32 + h;
  float s = 0.f, ss = 0.f;
  #pragma unroll
  for (int j = 0; j < 2; ++j) {
    const float2 pr = ((const float2*)part)[(bh << 1) + j];
    s += pr.x; ss += pr.y;
  }
  const float mean = s * (1.f / 65536.f);
  const float rstd = rsqrtf(ss * (1.f / 65536.f) - mean * mean + 0.00064f);
  const int c0 = tid << 3;
  const size_t base = (size_t)row * 2048 + c0;
  float yv[8], vv[8];
  float p = 0.f;
  #pragma unroll
  for (int e = 0; e < 8; ++e) {
    yv[e] = y[base + e];
    vv[e] = vf[base + e];
    const unsigned w_ = rkB[base + e];
    p = fmaf(h2f(w_ & 0xffffu) * h2f(w_ >> 16), r_k[c0 + e], p);
  }
  p += __shfl_xor(p, 1);
  p += __shfl_xor(p, 2);
  p += __shfl_xor(p, 4);
  #pragma unroll
  for (int e = 0; e < 8; ++e) {
    const float yn = (yv[e] - mean) * rstd;
    xxb[base + e] = f2b(fmaf(yn, ln_w[c0 + e], ln_b[c0 + e]) + p * vv[e]);
  }
}

// ---------------------------------------------------------------------------
extern "C" void kernel_launch(void* const* d_in, const int* in_sizes, int n_in,
                              void* d_out, int out_size, void* d_ws, size_t ws_size,
                              hipStream_t stream) {
  const float* x       = (const float*)d_in[0];
  const float* v_first = (const float*)d_in[1];
  const float* state   = (const float*)d_in[2];
  const float* Rw      = (const float*)d_in[3];
  const float* R_bias  = (const float*)d_in[4];
  const float* Kw      = (const float*)d_in[5];
  const float* K_bias  = (const float*)d_in[6];
  const float* Vw      = (const float*)d_in[7];
  const float* V_bias  = (const float*)d_in[8];
  const float* Ow      = (const float*)d_in[9];
  const float* O_bias  = (const float*)d_in[10];
  const float* w0      = (const float*)d_in[11];
  const float* w1      = (const float*)d_in[12];
  const float* w2      = (const float*)d_in[13];
  const float* a0      = (const float*)d_in[14];
  const float* a1      = (const float*)d_in[15];
  const float* a2      = (const float*)d_in[16];
  const float* v0      = (const float*)d_in[17];
  const float* v1      = (const float*)d_in[18];
  const float* v2      = (const float*)d_in[19];
  const float* k_k     = (const float*)d_in[20];
  const float* k_a     = (const float*)d_in[21];
  const float* r_k     = (const float*)d_in[22];
  const float* ln_w    = (const float*)d_in[23];
  const float* ln_b    = (const float*)d_in[24];

  float* ws = (float*)d_ws;
  float* r_buf = ws;                    // 8388608
  float* k_buf = r_buf + 8388608;       // 2097152
  float* v_buf = k_buf + 2097152;       // 2097152
  float* wt    = v_buf + 2097152;       // 8388608 (u -> decay in place, f32)
  float* at    = wt    + 8388608;       // 8388608 (a pre-act -> y after scan)
  float* vt    = at    + 8388608;       // 8388608 (v pre-act -> v_final, f32)
  float* kf    = vt    + 8388608;       // 8388608 (bf16 alias region)
  float* aaq   = kf    + 8388608;       // 8388608 -> rk_pk (u32)
  float* bbq   = aaq   + 8388608;       // 8388608 -> ab_pk (u32)
  float* part  = bbq   + 8388608;       // 2048 (gnorm partials)
  // bf16 aliases into the kf region (all 16B-aligned, disjoint):
  unsigned short* xb   = (unsigned short*)bbq;               // dead before prep
  unsigned short* RKVb = (unsigned short*)kf;                // [0 .. 3,145,728) fl
  unsigned short* Bcat = RKVb + 3072 * 2048;                 // contiguous after RKVb
  unsigned short* hcat = (unsigned short*)(kf + 3400000);    // 4096x160 bf16
  unsigned short* w2t  = (unsigned short*)(kf + 3800000);    // 2048x64
  unsigned short* a2t  = (unsigned short*)(kf + 3900000);    // 2048x64
  unsigned short* v2t  = (unsigned short*)(kf + 4000000);    // 2048x32
  unsigned short* Ob   = (unsigned short*)(kf + 4500000);    // 2048x2048 bf16
  unsigned* rk_pk      = (unsigned*)aaq;                     // packed f16 k|r
  unsigned* ab_pk      = (unsigned*)bbq;                     // packed f16 aa|bb
  unsigned short* xxb  = (unsigned short*)bbq;               // after scan

  dim3 blk(256);
  // ---- converts (x, R|K|V, Ow all in one launch) ----
  cvt4_kernel<<<18432, blk, 0, stream>>>(x, Rw, Kw, Vw, Ow, xb, RKVb, Ob);
  tcvt_all<<<192, blk, 0, stream>>>(w1, a1, v1, w2, a2, v2, Bcat, w2t, a2t, v2t);
  // ---- merged R|K|V|H projection (absorbs lr1; XCD-swizzled 1-D grid) ----
  gemm_rkvh<<<832, blk, 0, stream>>>(xb, RKVb, R_bias, K_bias, V_bias,
                                     r_buf, k_buf, v_buf, hcat);
  // ---- low-rank stage 2 (w|a|v merged into one launch) ----
  gemm_lr2<<<dim3(16, 32, 3), blk, 0, stream>>>(hcat, w2t, a2t, v2t, wt, at, vt);
  // ---- elementwise prep (writes packed f16 streams) ----
  prep_kernel<<<4096, blk, 0, stream>>>(k_buf, v_buf, r_buf, wt, at, vt, v_first,
                                        w0, a0, v0, k_k, k_a, rk_pk, ab_pk);
  // ---- recurrent scan (2 rows/lane, depth-2 pipeline; y reuses `at`) ----
  float* ybuf = at;
  scan_kernel<<<256, blk, 0, stream>>>(rk_pk, ab_pk, wt, vt, state, ybuf, part);
  // ---- group norm pass B + bonus -> bf16 xx (into bbq; ab_pk dead) ----
  gapply_kernel<<<4096, blk, 0, stream>>>(ybuf, rk_pk, vt, part, r_k,
                                          ln_w, ln_b, xxb);
  // ---- output projection (XCD-swizzled 1-D grid) ----
  gemm_out<<<512, blk, 0, stream>>>(xxb, Ob, O_bias, (float*)d_out);
}